// Round 5
// baseline (32248.361 us; speedup 1.0000x reference)
//
#include <hip/hip_runtime.h>

#define IN_   16
#define HID_  50
#define G4_   200   // 4*HID
#define T_    128
#define NCLS_ 20
#define BPB_  16    // batches per block
#define NTHR_ 256
#define GPAD_ 17    // gate LDS row stride (odd -> conflict-free)
#define XPAD_ 20    // x LDS row stride (80B: 16B-aligned rows, spreads write banks)

#define SBAR __builtin_amdgcn_sched_barrier(0)

__device__ __forceinline__ float fast_tanh(float v) {
    float e = __builtin_amdgcn_exp2f(2.8853900817779268f * v);   // e^(2v)
    return fmaf(-2.0f, __builtin_amdgcn_rcpf(e + 1.0f), 1.0f);
}

#define REP16(OP) OP(0) OP(1) OP(2) OP(3) OP(4) OP(5) OP(6) OP(7) \
                  OP(8) OP(9) OP(10) OP(11) OP(12) OP(13) OP(14) OP(15)

// 16 batch-fmas from one LDS row into named scalar accumulators a0..a15.
// RPTR is wave-uniform -> broadcast ds_read_b128, conflict-free.
#define FMA16(RPTR, W) do {                                              \
    const float4* _r = (const float4*)(RPTR);                            \
    const float4 _r0 = _r[0], _r1 = _r[1], _r2 = _r[2], _r3 = _r[3];     \
    a0  = fmaf(_r0.x,(W),a0);  a1  = fmaf(_r0.y,(W),a1);                 \
    a2  = fmaf(_r0.z,(W),a2);  a3  = fmaf(_r0.w,(W),a3);                 \
    a4  = fmaf(_r1.x,(W),a4);  a5  = fmaf(_r1.y,(W),a5);                 \
    a6  = fmaf(_r1.z,(W),a6);  a7  = fmaf(_r1.w,(W),a7);                 \
    a8  = fmaf(_r2.x,(W),a8);  a9  = fmaf(_r2.y,(W),a9);                 \
    a10 = fmaf(_r2.z,(W),a10); a11 = fmaf(_r2.w,(W),a11);                \
    a12 = fmaf(_r3.x,(W),a12); a13 = fmaf(_r3.y,(W),a13);                \
    a14 = fmaf(_r3.z,(W),a14); a15 = fmaf(_r3.w,(W),a15);                \
} while (0)

// min 3 waves/EU -> VGPR cap ~170: 12 waves/CU without spill risk.
// (NOT 4: demand is ~130-150; a 128 cap would re-trigger the R1-R3 spill.)
__global__ __launch_bounds__(NTHR_, 3)
void lstm_fused(const float* __restrict__ x,
                const float* __restrict__ W_ih,
                const float* __restrict__ W_hh,
                const float* __restrict__ b_ih,
                const float* __restrict__ b_hh,
                const float* __restrict__ W_fc,
                const float* __restrict__ b_fc,
                float* __restrict__ out)
{
    __shared__ __align__(16) float h_lds[HID_][BPB_];
    __shared__ __align__(16) float x_lds[IN_][XPAD_];
    __shared__ float g_lds[G4_][GPAD_];

    const int tid = threadIdx.x;
    const int b0  = blockIdx.x * BPB_;

    // ---- per-gate weights: whole row in NAMED VGPR scalars, loaded once.
    const int grow = (tid < G4_) ? tid : 0;      // clamp tail wave to a valid row
    const float* wrow  = W_hh + grow * HID_;
    const float* wirow = W_ih + grow * IN_;

    #define LDWH(k) const float wh##k = wrow[k];
    LDWH(0) LDWH(1) LDWH(2) LDWH(3) LDWH(4) LDWH(5) LDWH(6) LDWH(7) LDWH(8) LDWH(9)
    LDWH(10) LDWH(11) LDWH(12) LDWH(13) LDWH(14) LDWH(15) LDWH(16) LDWH(17) LDWH(18) LDWH(19)
    LDWH(20) LDWH(21) LDWH(22) LDWH(23) LDWH(24) LDWH(25) LDWH(26) LDWH(27) LDWH(28) LDWH(29)
    LDWH(30) LDWH(31) LDWH(32) LDWH(33) LDWH(34) LDWH(35) LDWH(36) LDWH(37) LDWH(38) LDWH(39)
    LDWH(40) LDWH(41) LDWH(42) LDWH(43) LDWH(44) LDWH(45) LDWH(46) LDWH(47) LDWH(48) LDWH(49)
    #undef LDWH

    const float4 wv0 = ((const float4*)wirow)[0];
    const float4 wv1 = ((const float4*)wirow)[1];
    const float4 wv2 = ((const float4*)wirow)[2];
    const float4 wv3 = ((const float4*)wirow)[3];
    const float wi0=wv0.x, wi1=wv0.y, wi2=wv0.z,  wi3=wv0.w;
    const float wi4=wv1.x, wi5=wv1.y, wi6=wv1.z,  wi7=wv1.w;
    const float wi8=wv2.x, wi9=wv2.y, wi10=wv2.z, wi11=wv2.w;
    const float wi12=wv3.x, wi13=wv3.y, wi14=wv3.z, wi15=wv3.w;

    const float bias = (tid < G4_) ? (b_ih[tid] + b_hh[tid]) : 0.0f;

    // one-exp activation: act(v) = s2 / (1 + 2^(v*sm)) + off
    //   sigmoid: sm=-log2e,  s2=1, off=0 ; tanh: sm=-2log2e, s2=2, off=-1
    const bool  isg = (tid >= 100) && (tid < 150);
    const float sm  = isg ? -2.8853900817779268f : -1.4426950408889634f;
    const float s2  = isg ? 2.0f : 1.0f;
    const float off = isg ? -1.0f : 0.0f;

    // ---- update-thread state
    const int uk = tid >> 2;
    const int ub = (tid & 3) << 2;
    float c0 = 0.f, c1 = 0.f, c2 = 0.f, c3 = 0.f;

    for (int idx = tid; idx < HID_ * BPB_; idx += NTHR_)
        ((float*)h_lds)[idx] = 0.0f;

    // ---- x loader mapping: 256 threads = 16 batches x 16 features
    const int xb = tid >> 4;
    const int xi = tid & 15;
    const float* xp = x + (size_t)(b0 + xb) * (T_ * IN_) + xi;
    x_lds[xi][xb] = xp[0];
    __syncthreads();

    for (int t = 0; t < T_; ++t) {
        float xv_next = 0.0f;
        if (t + 1 < T_) xv_next = xp[(size_t)(t + 1) * IN_];

        {
            float a0,a1,a2,a3,a4,a5,a6,a7,a8,a9,a10,a11,a12,a13,a14,a15;
            #define INIT1(k) a##k = bias;
            REP16(INIT1)
            #undef INIT1

            // input projection (16 rows). sched_barrier every 8 rows bounds
            // the hoisting window -> bounded register pressure, no spill.
            #define FI(k) FMA16(&x_lds[k][0], wi##k);
            FI(0) FI(1) FI(2) FI(3) FI(4) FI(5) FI(6) FI(7)
            SBAR;
            FI(8) FI(9) FI(10) FI(11) FI(12) FI(13) FI(14) FI(15)
            SBAR;
            #undef FI

            // recurrent matmul (50 rows), weights in registers
            #define FH(j) FMA16(&h_lds[j][0], wh##j);
            FH(0) FH(1) FH(2) FH(3) FH(4) FH(5) FH(6) FH(7) FH(8) FH(9)
            SBAR;
            FH(10) FH(11) FH(12) FH(13) FH(14) FH(15) FH(16) FH(17) FH(18) FH(19)
            SBAR;
            FH(20) FH(21) FH(22) FH(23) FH(24) FH(25) FH(26) FH(27) FH(28) FH(29)
            SBAR;
            FH(30) FH(31) FH(32) FH(33) FH(34) FH(35) FH(36) FH(37) FH(38) FH(39)
            SBAR;
            FH(40) FH(41) FH(42) FH(43) FH(44) FH(45) FH(46) FH(47) FH(48) FH(49)
            SBAR;
            #undef FH

            #define ACT1(k) a##k = fmaf(s2, __builtin_amdgcn_rcpf(1.0f + __builtin_amdgcn_exp2f(a##k * sm)), off);
            REP16(ACT1)
            #undef ACT1

            if (tid < G4_) {
                #define ST1(k) g_lds[tid][k] = a##k;
                REP16(ST1)
                #undef ST1
            }
        }
        __syncthreads();   // gates ready

        if (tid < G4_) {
            const float i0 = g_lds[uk      ][ub+0], i1 = g_lds[uk      ][ub+1],
                        i2 = g_lds[uk      ][ub+2], i3 = g_lds[uk      ][ub+3];
            const float f0 = g_lds[ 50 + uk][ub+0], f1 = g_lds[ 50 + uk][ub+1],
                        f2 = g_lds[ 50 + uk][ub+2], f3 = g_lds[ 50 + uk][ub+3];
            const float g0 = g_lds[100 + uk][ub+0], g1 = g_lds[100 + uk][ub+1],
                        g2 = g_lds[100 + uk][ub+2], g3 = g_lds[100 + uk][ub+3];
            const float o0 = g_lds[150 + uk][ub+0], o1 = g_lds[150 + uk][ub+1],
                        o2 = g_lds[150 + uk][ub+2], o3 = g_lds[150 + uk][ub+3];
            c0 = fmaf(f0, c0, i0 * g0);
            c1 = fmaf(f1, c1, i1 * g1);
            c2 = fmaf(f2, c2, i2 * g2);
            c3 = fmaf(f3, c3, i3 * g3);
            float4 hv;
            hv.x = o0 * fast_tanh(c0);
            hv.y = o1 * fast_tanh(c1);
            hv.z = o2 * fast_tanh(c2);
            hv.w = o3 * fast_tanh(c3);
            *(float4*)(&h_lds[uk][ub]) = hv;
        }
        x_lds[xi][xb] = xv_next;
        __syncthreads();           // h + next x ready
    }

    // ---- FC head: 16 batches x 20 classes per block
    for (int p = tid; p < BPB_ * NCLS_; p += NTHR_) {
        const int b  = p / NCLS_;
        const int cl = p % NCLS_;
        float acc = b_fc[cl];
        #pragma unroll
        for (int j = 0; j < HID_; ++j) {
            float hv = fmaxf(h_lds[j][b], 0.0f);   // relu
            acc = fmaf(hv, W_fc[cl * HID_ + j], acc);
        }
        out[(size_t)(b0 + b) * NCLS_ + cl] = acc;
    }
}

extern "C" void kernel_launch(void* const* d_in, const int* in_sizes, int n_in,
                              void* d_out, int out_size, void* d_ws, size_t ws_size,
                              hipStream_t stream) {
    const float* x    = (const float*)d_in[0];
    const float* W_ih = (const float*)d_in[1];
    const float* W_hh = (const float*)d_in[2];
    const float* b_ih = (const float*)d_in[3];
    const float* b_hh = (const float*)d_in[4];
    const float* W_fc = (const float*)d_in[5];
    const float* b_fc = (const float*)d_in[6];
    float* out = (float*)d_out;

    const int B = in_sizes[0] / (T_ * IN_);   // 8192
    dim3 grid(B / BPB_), block(NTHR_);
    hipLaunchKernelGGL(lstm_fused, grid, block, 0, stream,
                       x, W_ih, W_hh, b_ih, b_hh, W_fc, b_fc, out);
}

// Round 6
// 656.597 us; speedup vs baseline: 49.1144x; 49.1144x over previous
//
#include <hip/hip_runtime.h>

#define IN_   16
#define HID_  50
#define G4_   200   // 4*HID
#define T_    128
#define NCLS_ 20
#define BPB_  16    // batches per block
#define NTHR_ 256
#define WSTR_ 204   // transposed weight LDS row stride (gates 200 + pad)
#define GPAD_ 20    // gate LDS row stride (80B -> float4-aligned rows)

__device__ __forceinline__ float fast_tanh(float v) {
    float e = __builtin_amdgcn_exp2f(2.8853900817779268f * v);   // e^(2v)
    return fmaf(-2.0f, __builtin_amdgcn_rcpf(e + 1.0f), 1.0f);
}

#define REP8(OP) OP(0) OP(1) OP(2) OP(3) OP(4) OP(5) OP(6) OP(7)

// One K-row: 8 h-values (2 broadcast b128) x 2 gate weights (1 b64) -> 16 fma.
// Accumulators are NAMED scalars a0..a7 / b0..b7 (spill-proof, R4 lesson).
#define FROW(HP, WP) do {                                                 \
    const float4 _h0 = ((const float4*)(HP))[0];                          \
    const float4 _h1 = ((const float4*)(HP))[1];                          \
    const float2 _w  = *(const float2*)(WP);                              \
    a0 = fmaf(_h0.x,_w.x,a0); a1 = fmaf(_h0.y,_w.x,a1);                   \
    a2 = fmaf(_h0.z,_w.x,a2); a3 = fmaf(_h0.w,_w.x,a3);                   \
    a4 = fmaf(_h1.x,_w.x,a4); a5 = fmaf(_h1.y,_w.x,a5);                   \
    a6 = fmaf(_h1.z,_w.x,a6); a7 = fmaf(_h1.w,_w.x,a7);                   \
    b0 = fmaf(_h0.x,_w.y,b0); b1 = fmaf(_h0.y,_w.y,b1);                   \
    b2 = fmaf(_h0.z,_w.y,b2); b3 = fmaf(_h0.w,_w.y,b3);                   \
    b4 = fmaf(_h1.x,_w.y,b4); b5 = fmaf(_h1.y,_w.y,b5);                   \
    b6 = fmaf(_h1.z,_w.y,b6); b7 = fmaf(_h1.w,_w.y,b7);                   \
} while (0)

// Plain launch_bounds (no min-waves): R5 showed a min-waves hint + small LDS
// makes the allocator chase occupancy and spill. LDS (72.3KB) caps us at
// 2 blocks/CU; registers are free to grow to ~demand (~90).
__global__ __launch_bounds__(NTHR_)
void lstm_fused(const float* __restrict__ x,
                const float* __restrict__ W_ih,
                const float* __restrict__ W_hh,
                const float* __restrict__ b_ih,
                const float* __restrict__ b_hh,
                const float* __restrict__ W_fc,
                const float* __restrict__ b_fc,
                float* __restrict__ out)
{
    __shared__ __align__(16) float h_lds[HID_][BPB_];   // [unit][batch]
    __shared__ __align__(16) float x_lds[IN_][BPB_];    // [feat][batch]
    __shared__ __align__(16) float g_lds[G4_][GPAD_];   // [gate][batch], f4-aligned
    __shared__ __align__(16) float whh_t[HID_ * WSTR_]; // TRANSPOSED [j][gate]
    __shared__ __align__(16) float wih_t[IN_  * WSTR_]; // TRANSPOSED [i][gate]

    const int tid = threadIdx.x;
    const int b0  = blockIdx.x * BPB_;

    // ---- stage weights TRANSPOSED into LDS once (coalesced global reads)
    for (int idx = tid; idx < G4_ * HID_; idx += NTHR_) {
        const int g = idx / HID_;
        const int j = idx - g * HID_;
        whh_t[j * WSTR_ + g] = W_hh[idx];
    }
    for (int idx = tid; idx < G4_ * IN_; idx += NTHR_) {
        const int g = idx >> 4;
        const int i = idx & 15;
        wih_t[i * WSTR_ + g] = W_ih[idx];
    }

    // ---- gate-thread mapping: t<200: pair p = t%100 -> gates (2p, 2p+1),
    //      half-batch hb = t/100 -> batches [hb*8, hb*8+8)
    const bool on  = (tid < G4_);
    const int  p   = on ? (tid % 100) : 0;
    const int  hb  = on ? (tid / 100) : 0;
    const int  p2  = 2 * p;           // gate A index; gate B = p2+1
    const int  hb8 = hb * 8;

    const float biasA = on ? (b_ih[p2]     + b_hh[p2])     : 0.0f;
    const float biasB = on ? (b_ih[p2 + 1] + b_hh[p2 + 1]) : 0.0f;

    // one-exp activation: act(v) = s2 / (1 + 2^(v*sm)) + off
    // gates 100..149 are tanh (p in [50,75)); others sigmoid. Pair shares type.
    const bool  isg = (p2 >= 100) && (p2 < 150);
    const float sm  = isg ? -2.8853900817779268f : -1.4426950408889634f;
    const float s2  = isg ? 2.0f : 1.0f;
    const float off = isg ? -1.0f : 0.0f;

    // ---- update-thread state: unit uk = tid/4, batches ub..ub+3
    const int uk = tid >> 2;
    const int ub = (tid & 3) << 2;
    float c0 = 0.f, c1 = 0.f, c2 = 0.f, c3 = 0.f;

    for (int idx = tid; idx < HID_ * BPB_; idx += NTHR_)
        ((float*)h_lds)[idx] = 0.0f;

    // ---- x loader: 256 threads = 16 batches x 16 features
    const int xb = tid >> 4;
    const int xi = tid & 15;
    const float* xp = x + (size_t)(b0 + xb) * (T_ * IN_) + xi;
    x_lds[xi][xb] = xp[0];
    __syncthreads();

    for (int t = 0; t < T_; ++t) {
        float xv_next = 0.0f;
        if (t + 1 < T_) xv_next = xp[(size_t)(t + 1) * IN_];

        if (on) {
            float a0,a1,a2,a3,a4,a5,a6,a7;   // gate A, 8 batches
            float b0_,b1,b2,b3,b4,b5,b6,b7;  // gate B
            #define b0 b0_
            a0=biasA; a1=biasA; a2=biasA; a3=biasA; a4=biasA; a5=biasA; a6=biasA; a7=biasA;
            b0=biasB; b1=biasB; b2=biasB; b3=biasB; b4=biasB; b5=biasB; b6=biasB; b7=biasB;

            // input projection (16 rows): bounded unroll -> bounded pressure
            #pragma unroll 4
            for (int i = 0; i < IN_; ++i)
                FROW(&x_lds[i][hb8], &wih_t[i * WSTR_ + p2]);

            // recurrent matmul (50 rows)
            #pragma unroll 4
            for (int j = 0; j < HID_; ++j)
                FROW(&h_lds[j][hb8], &whh_t[j * WSTR_ + p2]);

            // activation in place (one exp2 + one rcp each)
            #define ACT1(k) \
                a##k = fmaf(s2, __builtin_amdgcn_rcpf(1.0f + __builtin_amdgcn_exp2f(a##k * sm)), off); \
                b##k = fmaf(s2, __builtin_amdgcn_rcpf(1.0f + __builtin_amdgcn_exp2f(b##k * sm)), off);
            REP8(ACT1)
            #undef ACT1

            // store gates: 4 aligned float4s
            *(float4*)(&g_lds[p2    ][hb8    ]) = make_float4(a0, a1, a2, a3);
            *(float4*)(&g_lds[p2    ][hb8 + 4]) = make_float4(a4, a5, a6, a7);
            *(float4*)(&g_lds[p2 + 1][hb8    ]) = make_float4(b0, b1, b2, b3);
            *(float4*)(&g_lds[p2 + 1][hb8 + 4]) = make_float4(b4, b5, b6, b7);
            #undef b0
        }
        __syncthreads();   // gates ready

        if (on) {
            const float4 iv = *(const float4*)(&g_lds[uk      ][ub]);
            const float4 fv = *(const float4*)(&g_lds[ 50 + uk][ub]);
            const float4 gv = *(const float4*)(&g_lds[100 + uk][ub]);
            const float4 ov = *(const float4*)(&g_lds[150 + uk][ub]);
            c0 = fmaf(fv.x, c0, iv.x * gv.x);
            c1 = fmaf(fv.y, c1, iv.y * gv.y);
            c2 = fmaf(fv.z, c2, iv.z * gv.z);
            c3 = fmaf(fv.w, c3, iv.w * gv.w);
            float4 hv;
            hv.x = ov.x * fast_tanh(c0);
            hv.y = ov.y * fast_tanh(c1);
            hv.z = ov.z * fast_tanh(c2);
            hv.w = ov.w * fast_tanh(c3);
            *(float4*)(&h_lds[uk][ub]) = hv;
        }
        x_lds[xi][xb] = xv_next;
        __syncthreads();           // h + next x ready
    }

    // ---- FC head: 16 batches x 20 classes per block
    for (int pp = tid; pp < BPB_ * NCLS_; pp += NTHR_) {
        const int b  = pp / NCLS_;
        const int cl = pp % NCLS_;
        float acc = b_fc[cl];
        #pragma unroll
        for (int j = 0; j < HID_; ++j) {
            float hv = fmaxf(h_lds[j][b], 0.0f);   // relu
            acc = fmaf(hv, W_fc[cl * HID_ + j], acc);
        }
        out[(size_t)(b0 + b) * NCLS_ + cl] = acc;
    }
}

extern "C" void kernel_launch(void* const* d_in, const int* in_sizes, int n_in,
                              void* d_out, int out_size, void* d_ws, size_t ws_size,
                              hipStream_t stream) {
    const float* x    = (const float*)d_in[0];
    const float* W_ih = (const float*)d_in[1];
    const float* W_hh = (const float*)d_in[2];
    const float* b_ih = (const float*)d_in[3];
    const float* b_hh = (const float*)d_in[4];
    const float* W_fc = (const float*)d_in[5];
    const float* b_fc = (const float*)d_in[6];
    float* out = (float*)d_out;

    const int B = in_sizes[0] / (T_ * IN_);   // 8192
    dim3 grid(B / BPB_), block(NTHR_);
    hipLaunchKernelGGL(lstm_fused, grid, block, 0, stream,
                       x, W_ih, W_hh, b_ih, b_hh, W_fc, b_fc, out);
}

// Round 7
// 534.436 us; speedup vs baseline: 60.3409x; 1.2286x over previous
//
#include <hip/hip_runtime.h>

#define IN_   16
#define HID_  50
#define G4_   200   // 4*HID
#define T_    128
#define NCLS_ 20
#define BPB_  16    // batches per block
#define NTHR_ 256
#define NROW_ 66    // 16 x-rows + 50 h-rows
#define WSTR_ 200   // weight LDS row stride (floats): [row][4u+k], k=i,f,g,o
#define SSTR_ 16    // state LDS row stride (floats)

#define L2E_  1.4426950408889634f
#define SIG1(v)  __builtin_amdgcn_rcpf(1.0f + __builtin_amdgcn_exp2f((v) * -L2E_))
#define TANH1(v) fmaf(2.0f, __builtin_amdgcn_rcpf(1.0f + __builtin_amdgcn_exp2f((v) * -2.0f * L2E_)), -1.0f)

// Plain launch_bounds: LDS (61.4KB) caps at 2 blocks/CU; leave the register
// ceiling free (R5 lesson: min-waves hint + spare LDS => allocator spills).
__global__ __launch_bounds__(NTHR_)
void lstm_fused(const float* __restrict__ x,
                const float* __restrict__ W_ih,
                const float* __restrict__ W_hh,
                const float* __restrict__ b_ih,
                const float* __restrict__ b_hh,
                const float* __restrict__ W_fc,
                const float* __restrict__ b_fc,
                float* __restrict__ out)
{
    // weights, gate-interleaved: w_all[r][4u+k] ; r<16 -> W_ih row r, else W_hh row r-16
    __shared__ __align__(16) float w_all[NROW_ * WSTR_];          // 52.8 KB
    // state, ping-pong: rows 0..15 = x[feat][batch], rows 16..65 = h[unit][batch]
    __shared__ __align__(16) float s_lds[2][NROW_ * SSTR_];       // 8.4 KB

    const int tid = threadIdx.x;
    const int b0  = blockIdx.x * BPB_;

    // ---- stage weights gate-interleaved (one time)
    for (int idx = tid; idx < G4_ * IN_; idx += NTHR_) {
        const int g = idx >> 4, i = idx & 15;
        w_all[i * WSTR_ + 4 * (g % HID_) + (g / HID_)] = W_ih[idx];
    }
    for (int idx = tid; idx < G4_ * HID_; idx += NTHR_) {
        const int g = idx / HID_, j = idx - g * HID_;
        w_all[(IN_ + j) * WSTR_ + 4 * (g % HID_) + (g / HID_)] = W_hh[idx];
    }

    // ---- thread mapping: tid<200 owns unit u = tid%50, batches bb..bb+3
    const bool on = (tid < G4_);
    const int  u  = on ? (tid % HID_) : 0;
    const int  bb = on ? ((tid / HID_) << 2) : 0;

    const float biasI = on ? (b_ih[u          ] + b_hh[u          ]) : 0.0f;
    const float biasF = on ? (b_ih[HID_   + u ] + b_hh[HID_   + u ]) : 0.0f;
    const float biasG = on ? (b_ih[2*HID_ + u ] + b_hh[2*HID_ + u ]) : 0.0f;
    const float biasO = on ? (b_ih[3*HID_ + u ] + b_hh[3*HID_ + u ]) : 0.0f;

    float c0 = 0.f, c1 = 0.f, c2 = 0.f, c3 = 0.f;

    // zero h rows of buffer 0
    for (int idx = tid; idx < HID_ * SSTR_; idx += NTHR_)
        s_lds[0][IN_ * SSTR_ + idx] = 0.0f;

    // ---- x loader: 256 threads = 16 features x 16 batches
    const int xi = tid & 15;          // feature -> state row
    const int xb = tid >> 4;          // batch   -> state col
    const float* xp = x + (size_t)(b0 + xb) * (T_ * IN_) + xi;
    s_lds[0][xi * SSTR_ + xb] = xp[0];
    __syncthreads();

    const float* wp = w_all + 4 * u;  // this unit's weight column

    for (int t = 0; t < T_; ++t) {
        const int cur = t & 1, nxt = cur ^ 1;
        const float* sc = s_lds[cur];

        float xv_next = 0.0f;
        if (t + 1 < T_) xv_next = xp[(size_t)(t + 1) * IN_];

        if (on) {
            float i0=biasI,i1=biasI,i2=biasI,i3=biasI;
            float f0=biasF,f1=biasF,f2=biasF,f3=biasF;
            float g0=biasG,g1=biasG,g2=biasG,g3=biasG;
            float o0=biasO,o1=biasO,o2=biasO,o3=biasO;

            // 66 rows x 16 fma; 2 ds_read_b128 per row. Bounded unroll ->
            // bounded scheduling window -> no spill (R4 lesson).
            #pragma unroll 4
            for (int r = 0; r < NROW_; ++r) {
                const float4 sv = *(const float4*)(sc + r * SSTR_ + bb);
                const float4 wv = *(const float4*)(wp + r * WSTR_);
                i0 = fmaf(sv.x, wv.x, i0); i1 = fmaf(sv.y, wv.x, i1);
                i2 = fmaf(sv.z, wv.x, i2); i3 = fmaf(sv.w, wv.x, i3);
                f0 = fmaf(sv.x, wv.y, f0); f1 = fmaf(sv.y, wv.y, f1);
                f2 = fmaf(sv.z, wv.y, f2); f3 = fmaf(sv.w, wv.y, f3);
                g0 = fmaf(sv.x, wv.z, g0); g1 = fmaf(sv.y, wv.z, g1);
                g2 = fmaf(sv.z, wv.z, g2); g3 = fmaf(sv.w, wv.z, g3);
                o0 = fmaf(sv.x, wv.w, o0); o1 = fmaf(sv.y, wv.w, o1);
                o2 = fmaf(sv.z, wv.w, o2); o3 = fmaf(sv.w, wv.w, o3);
            }

            // activations: gate type is compile-time per accumulator (no selects)
            i0 = SIG1(i0); i1 = SIG1(i1); i2 = SIG1(i2); i3 = SIG1(i3);
            f0 = SIG1(f0); f1 = SIG1(f1); f2 = SIG1(f2); f3 = SIG1(f3);
            g0 = TANH1(g0); g1 = TANH1(g1); g2 = TANH1(g2); g3 = TANH1(g3);
            o0 = SIG1(o0); o1 = SIG1(o1); o2 = SIG1(o2); o3 = SIG1(o3);

            // c/h update fully in-register (g_lds round-trip eliminated)
            c0 = fmaf(f0, c0, i0 * g0);
            c1 = fmaf(f1, c1, i1 * g1);
            c2 = fmaf(f2, c2, i2 * g2);
            c3 = fmaf(f3, c3, i3 * g3);
            float4 hv;
            hv.x = o0 * TANH1(c0);
            hv.y = o1 * TANH1(c1);
            hv.z = o2 * TANH1(c2);
            hv.w = o3 * TANH1(c3);
            *(float4*)(&s_lds[nxt][(IN_ + u) * SSTR_ + bb]) = hv;
        }
        // next step's x into the other buffer (no read/write overlap)
        s_lds[nxt][xi * SSTR_ + xb] = xv_next;
        __syncthreads();   // ONE barrier per step
    }

    // final h lives in buffer 0 (t=127: cur=1 -> wrote nxt=0)
    const float* hf = s_lds[0] + IN_ * SSTR_;

    // ---- FC head: 16 batches x 20 classes per block
    for (int p = tid; p < BPB_ * NCLS_; p += NTHR_) {
        const int b  = p / NCLS_;
        const int cl = p % NCLS_;
        float acc = b_fc[cl];
        #pragma unroll
        for (int j = 0; j < HID_; ++j) {
            float hv = fmaxf(hf[j * SSTR_ + b], 0.0f);   // relu
            acc = fmaf(hv, W_fc[cl * HID_ + j], acc);
        }
        out[(size_t)(b0 + b) * NCLS_ + cl] = acc;
    }
}

extern "C" void kernel_launch(void* const* d_in, const int* in_sizes, int n_in,
                              void* d_out, int out_size, void* d_ws, size_t ws_size,
                              hipStream_t stream) {
    const float* x    = (const float*)d_in[0];
    const float* W_ih = (const float*)d_in[1];
    const float* W_hh = (const float*)d_in[2];
    const float* b_ih = (const float*)d_in[3];
    const float* b_hh = (const float*)d_in[4];
    const float* W_fc = (const float*)d_in[5];
    const float* b_fc = (const float*)d_in[6];
    float* out = (float*)d_out;

    const int B = in_sizes[0] / (T_ * IN_);   // 8192
    dim3 grid(B / BPB_), block(NTHR_);
    hipLaunchKernelGGL(lstm_fused, grid, block, 0, stream,
                       x, W_ih, W_hh, b_ih, b_hh, W_fc, b_fc, out);
}

// Round 8
// 419.654 us; speedup vs baseline: 76.8451x; 1.2735x over previous
//
#include <hip/hip_runtime.h>

#define IN_   16
#define HID_  50
#define G4_   200   // 4*HID
#define T_    128
#define NCLS_ 20
#define BPB_  8     // batches per block (grid 1024 -> 4 blocks/CU resident)
#define NTHR_ 256
#define NRP_  33    // (16 x-rows + 50 h-rows) / 2 row-pairs
#define WSTR_ 256   // u32 stride per row-pair (200 used; pad keeps LDS ~36KB)

#define L2E_ 1.4426950408889634f

typedef unsigned int u32;
typedef _Float16 h2_t __attribute__((ext_vector_type(2)));

__device__ __forceinline__ h2_t as_h2(u32 v) { union { u32 u; h2_t h; } x; x.u = v; return x.h; }
__device__ __forceinline__ float sig1(float v)  { return __builtin_amdgcn_rcpf(1.0f + __builtin_amdgcn_exp2f(v * -L2E_)); }
__device__ __forceinline__ float tanh1(float v) { return fmaf(2.0f, __builtin_amdgcn_rcpf(1.0f + __builtin_amdgcn_exp2f(v * (-2.0f * L2E_))), -1.0f); }

#define FDOT2(S, W, ACC) __builtin_amdgcn_fdot2(as_h2(S), as_h2(W), (ACC), false)

// Plain launch_bounds; LDS (~36KB) pins 4 blocks/CU, register demand ~50 -> no
// spill pressure in either the 64- or 128-reg occupancy class (R4/R5 lessons).
__global__ __launch_bounds__(NTHR_)
void lstm_fused(const float* __restrict__ x,
                const float* __restrict__ W_ih,
                const float* __restrict__ W_hh,
                const float* __restrict__ b_ih,
                const float* __restrict__ b_hh,
                const float* __restrict__ W_fc,
                const float* __restrict__ b_fc,
                float* __restrict__ out)
{
    // weights: [rp][4u+k] = half2(W[row 2rp][gate], W[row 2rp+1][gate]), k=i,f,g,o
    __shared__ __align__(16) u32 w2[NRP_ * WSTR_];      // 33.8 KB
    // state ping-pong: [rp][batch] = half2(state[2rp][b], state[2rp+1][b])
    // rows 0..15 = x features, rows 16..65 = h units
    __shared__ __align__(16) u32 s2[2][NRP_ * BPB_];    // 2.1 KB

    const int tid = threadIdx.x;
    const int b0  = blockIdx.x * BPB_;

    // ---- stage weights as fp16 row-pairs, gate-interleaved (one time, RNE)
    for (int idx = tid; idx < NRP_ * G4_; idx += NTHR_) {
        const int rp = idx / G4_, gi = idx - rp * G4_;
        const int u = gi >> 2, k = gi & 3, g = k * HID_ + u;
        const int r0 = 2 * rp, r1 = r0 + 1;
        const float w0 = (r0 < IN_) ? W_ih[g * IN_ + r0] : W_hh[g * HID_ + (r0 - IN_)];
        const float w1 = (r1 < IN_) ? W_ih[g * IN_ + r1] : W_hh[g * HID_ + (r1 - IN_)];
        union { u32 u_; h2_t h; } p;
        p.h[0] = (_Float16)w0; p.h[1] = (_Float16)w1;
        w2[rp * WSTR_ + gi] = p.u_;
    }

    // ---- thread map: tid<200 -> unit u = tid>>2 (wave-local 16 distinct
    // weight addrs = 2-way bank alias = free), batches bb, bb+1
    const bool on = (tid < G4_);
    const int  u  = on ? (tid >> 2) : 0;
    const int  bb = on ? ((tid & 3) << 1) : 0;

    const float biasI = on ? (b_ih[u           ] + b_hh[u           ]) : 0.0f;
    const float biasF = on ? (b_ih[HID_   + u  ] + b_hh[HID_   + u  ]) : 0.0f;
    const float biasG = on ? (b_ih[2*HID_ + u  ] + b_hh[2*HID_ + u  ]) : 0.0f;
    const float biasO = on ? (b_ih[3*HID_ + u  ] + b_hh[3*HID_ + u  ]) : 0.0f;

    float c0 = 0.f, c1 = 0.f;

    // zero h rows of buffer 0
    for (int idx = tid; idx < NRP_ * BPB_; idx += NTHR_)
        s2[0][idx] = 0u;

    // ---- x loader: 64 threads = 8 batches x 8 feature-pairs (float2 global)
    const int xb = tid >> 3;          // batch
    const int fp = tid & 7;           // feature pair -> state row-pair fp
    const float* xp = x + (size_t)(b0 + xb) * (T_ * IN_) + 2 * fp;
    if (tid < 64) {
        const float2 xv = *(const float2*)xp;
        union { u32 u_; h2_t h; } p;
        p.h[0] = (_Float16)xv.x; p.h[1] = (_Float16)xv.y;
        s2[0][fp * BPB_ + xb] = p.u_;
    }
    __syncthreads();

    const u32* wp = w2 + 4 * u;       // this unit's 4-gate weight column

    for (int t = 0; t < T_; ++t) {
        const int cur = t & 1, nxt = cur ^ 1;
        const u32* sc = s2[cur];

        float2 xn = make_float2(0.f, 0.f);
        if (t + 1 < T_ && tid < 64) xn = *(const float2*)(xp + (size_t)(t + 1) * IN_);

        if (on) {
            float i0=biasI, i1=biasI, f0=biasF, f1=biasF;
            float g0=biasG, g1=biasG, o0=biasO, o1=biasO;

            // 33 row-pairs: 1 b64 state read + 1 b128 weight read + 8 dot2
            // (16 MACs) each. Bounded unroll -> bounded scheduling window.
            #pragma unroll 3
            for (int rp = 0; rp < NRP_; ++rp) {
                const uint2 sv = *(const uint2*)(sc + rp * BPB_ + bb);
                const uint4 wv = *(const uint4*)(wp + rp * WSTR_);
                i0 = FDOT2(sv.x, wv.x, i0);  i1 = FDOT2(sv.y, wv.x, i1);
                f0 = FDOT2(sv.x, wv.y, f0);  f1 = FDOT2(sv.y, wv.y, f1);
                g0 = FDOT2(sv.x, wv.z, g0);  g1 = FDOT2(sv.y, wv.z, g1);
                o0 = FDOT2(sv.x, wv.w, o0);  o1 = FDOT2(sv.y, wv.w, o1);
            }

            i0 = sig1(i0);  i1 = sig1(i1);
            f0 = sig1(f0);  f1 = sig1(f1);
            g0 = tanh1(g0); g1 = tanh1(g1);
            o0 = sig1(o0);  o1 = sig1(o1);

            c0 = fmaf(f0, c0, i0 * g0);
            c1 = fmaf(f1, c1, i1 * g1);
            const float hv0 = o0 * tanh1(c0);
            const float hv1 = o1 * tanh1(c1);

            // h row 16+u -> row-pair 8+(u>>1), half u&1 : two b16 writes
            _Float16* hp = (_Float16*)(s2[nxt]);
            const int hbase = (8 + (u >> 1)) * BPB_;
            hp[(hbase + bb    ) * 2 + (u & 1)] = (_Float16)hv0;
            hp[(hbase + bb + 1) * 2 + (u & 1)] = (_Float16)hv1;
        }
        if (tid < 64) {
            union { u32 u_; h2_t h; } p;
            p.h[0] = (_Float16)xn.x; p.h[1] = (_Float16)xn.y;
            s2[nxt][fp * BPB_ + xb] = p.u_;
        }
        __syncthreads();   // one barrier per step
    }

    // final h is in buffer 0 (t=127 wrote nxt=0)
    const _Float16* hf = (const _Float16*)(s2[0]);

    // ---- FC head: 8 batches x 20 classes per block
    for (int p = tid; p < BPB_ * NCLS_; p += NTHR_) {
        const int b  = p / NCLS_;
        const int cl = p % NCLS_;
        float acc = b_fc[cl];
        #pragma unroll
        for (int j = 0; j < HID_; ++j) {
            const float hv = fmaxf((float)hf[((8 + (j >> 1)) * BPB_ + b) * 2 + (j & 1)], 0.0f);
            acc = fmaf(hv, W_fc[cl * HID_ + j], acc);
        }
        out[(size_t)(b0 + b) * NCLS_ + cl] = acc;
    }
}

extern "C" void kernel_launch(void* const* d_in, const int* in_sizes, int n_in,
                              void* d_out, int out_size, void* d_ws, size_t ws_size,
                              hipStream_t stream) {
    const float* x    = (const float*)d_in[0];
    const float* W_ih = (const float*)d_in[1];
    const float* W_hh = (const float*)d_in[2];
    const float* b_ih = (const float*)d_in[3];
    const float* b_hh = (const float*)d_in[4];
    const float* W_fc = (const float*)d_in[5];
    const float* b_fc = (const float*)d_in[6];
    float* out = (float*)d_out;

    const int B = in_sizes[0] / (T_ * IN_);   // 8192
    dim3 grid(B / BPB_), block(NTHR_);
    hipLaunchKernelGGL(lstm_fused, grid, block, 0, stream,
                       x, W_ih, W_hh, b_ih, b_hh, W_fc, b_fc, out);
}

// Round 9
// 121.375 us; speedup vs baseline: 265.6922x; 3.4575x over previous
//
#include <hip/hip_runtime.h>

#define IN_    16
#define HID_   50
#define T_     128
#define NCLS_  20
#define BPB_   16     // batches per block = MFMA N
#define NTHR_  512    // 8 waves
#define NTILE_ 16     // 16 M-tiles of 16 gate-slots (64 unit-slots, 50 real)
#define NQ_    3      // K chunks of 32 (96 >= 16+50)
#define KP_    104    // state row stride in halves (208B = 16B-aligned, 2-way banks)
#define STSZ_  (BPB_ * KP_)

typedef _Float16 half8 __attribute__((ext_vector_type(8)));
typedef float    f32x4 __attribute__((ext_vector_type(4)));
typedef unsigned int u32;

#define L2E_ 1.4426950408889634f
__device__ __forceinline__ float sig1(float v)  { return __builtin_amdgcn_rcpf(1.0f + __builtin_amdgcn_exp2f(v * -L2E_)); }
__device__ __forceinline__ float tanh1(float v) { return fmaf(2.0f, __builtin_amdgcn_rcpf(1.0f + __builtin_amdgcn_exp2f(v * (-2.0f * L2E_))), -1.0f); }

#define MFMA(A, B, C) __builtin_amdgcn_mfma_f32_16x16x32_f16((A), (B), (C), 0, 0, 0)

// Plain launch_bounds (R5 lesson). LDS 55.8KB -> 2 blocks/CU, grid 512 = exact fit.
__global__ __launch_bounds__(NTHR_)
void lstm_mfma(const float* __restrict__ x,
               const float* __restrict__ W_ih,
               const float* __restrict__ W_hh,
               const float* __restrict__ b_ih,
               const float* __restrict__ b_hh,
               const float* __restrict__ W_fc,
               const float* __restrict__ b_fc,
               float* __restrict__ out)
{
    // weight A-fragments, fragment-linear: chunk = tile*3+q; lane's 8 halves 16B-contiguous
    __shared__ __align__(16) _Float16 wfrag[NTILE_ * NQ_ * 64 * 8];   // 48 KB
    // state ping-pong: st[buf][batch*KP_ + k]; k: 0..15 = x, 16..65 = h, 66..95 = zero pad
    __shared__ __align__(16) _Float16 st[2][STSZ_];                   // 6.5 KB

    const int tid  = threadIdx.x;
    const int lane = tid & 63;
    const int wv   = tid >> 6;          // wave 0..7, owns tiles 2wv, 2wv+1
    const int b0   = blockIdx.x * BPB_;

    // ---- stage weight fragments (one time). Gate slot s=tile*16+row interleaved:
    //      unit u = s>>2, gate-kind kk = s&3, torch gate index g = kk*50+u.
    u32* wf32 = (u32*)wfrag;
    for (int idx = tid; idx < NTILE_ * NQ_ * 64 * 4; idx += NTHR_) {
        const int j    = idx & 3;                 // u32 within lane's 16B
        const int ln   = (idx >> 2) & 63;
        const int chnk = idx >> 8;                // tile*3 + q
        const int tile = chnk / 3, q = chnk - 3 * tile;
        const int s  = tile * 16 + (ln & 15);     // A row (M) = lane&15
        const int u  = s >> 2, kk = s & 3;
        const int k0 = q * 32 + (ln >> 4) * 8 + 2 * j;   // A k = (lane>>4)*8+e
        float w0 = 0.f, w1 = 0.f;
        if (u < HID_) {
            const int g = kk * HID_ + u;
            if (k0 < IN_)                w0 = W_ih[g * IN_ + k0];
            else if (k0 < IN_ + HID_)    w0 = W_hh[g * HID_ + (k0 - IN_)];
            const int k1 = k0 + 1;
            if (k1 < IN_)                w1 = W_ih[g * IN_ + k1];
            else if (k1 < IN_ + HID_)    w1 = W_hh[g * HID_ + (k1 - IN_)];
        }
        union { u32 u_; _Float16 h[2]; } p;
        p.h[0] = (_Float16)w0; p.h[1] = (_Float16)w1;
        wf32[idx] = p.u_;
    }

    // ---- zero both state buffers (h(0)=0 and the K pad must stay zero forever)
    for (int idx = tid; idx < 2 * STSZ_ / 2; idx += NTHR_)
        ((u32*)st)[idx] = 0u;

    // ---- per-wave unit ids + biases (C/D rows (lane>>4)*4+reg = unit's i,f,g,o)
    const int u0 = (2 * wv    ) * 4 + (lane >> 4);
    const int u1 = (2 * wv + 1) * 4 + (lane >> 4);
    f32x4 bias0 = {0.f, 0.f, 0.f, 0.f}, bias1 = {0.f, 0.f, 0.f, 0.f};
    #pragma unroll
    for (int kk = 0; kk < 4; ++kk) {
        if (u0 < HID_) bias0[kk] = b_ih[kk * HID_ + u0] + b_hh[kk * HID_ + u0];
        if (u1 < HID_) bias1[kk] = b_ih[kk * HID_ + u1] + b_hh[kk * HID_ + u1];
    }
    float c0_ = 0.f, c1_ = 0.f;                  // cell state, lane-local

    __syncthreads();   // zero-fill visible before x(0) write (different threads)

    // ---- x loader: 256 threads = 16 batches x 16 features, fp16 into state rows 0..15
    const int xb = (tid >> 4) & 15;
    const int xf = tid & 15;
    const float* xp = x + (size_t)(b0 + xb) * (T_ * IN_) + xf;
    if (tid < 256) st[0][xb * KP_ + xf] = (_Float16)xp[0];
    __syncthreads();

    // B-fragment address: col(batch)=lane&15, k=(lane>>4)*8+e -> 16B-aligned half8
    const int brow = (lane & 15) * KP_ + (lane >> 4) * 8;
    const _Float16* wbase = wfrag + (size_t)(6 * wv) * 512 + lane * 8;
    const int hrow0 = (lane & 15) * KP_ + IN_ + u0;
    const int hrow1 = (lane & 15) * KP_ + IN_ + u1;

    for (int t = 0; t < T_; ++t) {
        const int cur = t & 1, nxt = cur ^ 1;
        const _Float16* sc = st[cur];
        _Float16*       sn = st[nxt];

        // B fragments: state K-chunks 0..2 (broadcast-ish reads, 2-way banks = free)
        const half8 B0 = *(const half8*)(sc + brow);
        const half8 B1 = *(const half8*)(sc + brow + 32);
        const half8 B2 = *(const half8*)(sc + brow + 64);

        // 6 MFMA: 2 tiles x 3 K-chunks; A reads are lane-linear (conflict-free)
        f32x4 C0 = bias0, C1 = bias1;
        half8 A;
        A = *(const half8*)(wbase + 0 * 512); C0 = MFMA(A, B0, C0);
        A = *(const half8*)(wbase + 1 * 512); C0 = MFMA(A, B1, C0);
        A = *(const half8*)(wbase + 2 * 512); C0 = MFMA(A, B2, C0);
        A = *(const half8*)(wbase + 3 * 512); C1 = MFMA(A, B0, C1);
        A = *(const half8*)(wbase + 4 * 512); C1 = MFMA(A, B1, C1);
        A = *(const half8*)(wbase + 5 * 512); C1 = MFMA(A, B2, C1);

        // activations + c/h update: fully lane-local (i,f,g,o = C[0..3])
        {
            const float iv = sig1(C0[0]), fv = sig1(C0[1]);
            const float gv = tanh1(C0[2]), ov = sig1(C0[3]);
            c0_ = fmaf(fv, c0_, iv * gv);
            const float hv = ov * tanh1(c0_);
            if (u0 < HID_) sn[hrow0] = (_Float16)hv;
        }
        {
            const float iv = sig1(C1[0]), fv = sig1(C1[1]);
            const float gv = tanh1(C1[2]), ov = sig1(C1[3]);
            c1_ = fmaf(fv, c1_, iv * gv);
            const float hv = ov * tanh1(c1_);
            if (u1 < HID_) sn[hrow1] = (_Float16)hv;
        }

        // next x into the other buffer
        if (tid < 256 && t + 1 < T_)
            sn[xb * KP_ + xf] = (_Float16)xp[(size_t)(t + 1) * IN_];

        __syncthreads();   // ONE barrier per step
    }

    // final h: t=127 wrote buffer 0 (rows 16..65, fp16)
    const _Float16* hf = st[0];

    // ---- FC head: 16 batches x 20 classes
    for (int p = tid; p < BPB_ * NCLS_; p += NTHR_) {
        const int b  = p / NCLS_;
        const int cl = p - b * NCLS_;
        float acc = b_fc[cl];
        #pragma unroll
        for (int j = 0; j < HID_; ++j) {
            const float hv = fmaxf((float)hf[b * KP_ + IN_ + j], 0.0f);   // relu
            acc = fmaf(hv, W_fc[cl * HID_ + j], acc);
        }
        out[(size_t)(b0 + b) * NCLS_ + cl] = acc;
    }
}

extern "C" void kernel_launch(void* const* d_in, const int* in_sizes, int n_in,
                              void* d_out, int out_size, void* d_ws, size_t ws_size,
                              hipStream_t stream) {
    const float* x    = (const float*)d_in[0];
    const float* W_ih = (const float*)d_in[1];
    const float* W_hh = (const float*)d_in[2];
    const float* b_ih = (const float*)d_in[3];
    const float* b_hh = (const float*)d_in[4];
    const float* W_fc = (const float*)d_in[5];
    const float* b_fc = (const float*)d_in[6];
    float* out = (float*)d_out;

    const int B = in_sizes[0] / (T_ * IN_);   // 8192
    dim3 grid(B / BPB_), block(NTHR_);
    hipLaunchKernelGGL(lstm_mfma, grid, block, 0, stream,
                       x, W_ih, W_hh, b_ih, b_hh, W_fc, b_fc, out);
}

// Round 10
// 115.444 us; speedup vs baseline: 279.3418x; 1.0514x over previous
//
#include <hip/hip_runtime.h>

#define IN_    16
#define HID_   50
#define T_     128
#define NCLS_  20
#define BPB_   16     // batches per block = MFMA N
#define NTHR_  1024   // 16 waves: 13 compute (1 M-tile each) + 3 x-loader
#define NTILE_ 13     // 13 tiles x 16 slots = 208 gate-slots (200 real)
#define NQ_    2      // K chunks of 32 -> K=64 via MFMA; rows 64,65 via fdot2 tail
#define KP_    72     // state row stride in halves (144B = 9x16B, 16B-aligned)
#define KPW_   36     // state row stride in u32

typedef _Float16 half8 __attribute__((ext_vector_type(8)));
typedef _Float16 h2_t  __attribute__((ext_vector_type(2)));
typedef float    f32x4 __attribute__((ext_vector_type(4)));
typedef unsigned int u32;

#define L2E_ 1.4426950408889634f
__device__ __forceinline__ float sig1(float v)  { return __builtin_amdgcn_rcpf(1.0f + __builtin_amdgcn_exp2f(v * -L2E_)); }
__device__ __forceinline__ float tanh1(float v) { return fmaf(2.0f, __builtin_amdgcn_rcpf(1.0f + __builtin_amdgcn_exp2f(v * (-2.0f * L2E_))), -1.0f); }
__device__ __forceinline__ h2_t as_h2(u32 v) { union { u32 u; h2_t h; } x; x.u = v; return x.h; }
__device__ __forceinline__ u32 pkh2(float a, float b) {
    union { u32 v; _Float16 h[2]; } p; p.h[0] = (_Float16)a; p.h[1] = (_Float16)b; return p.v;
}
#define FDOT2(S, W, ACC) __builtin_amdgcn_fdot2(as_h2(S), as_h2(W), (ACC), false)
#define MFMA(A, B, C) __builtin_amdgcn_mfma_f32_16x16x32_f16((A), (B), (C), 0, 0, 0)

// (1024, 8 waves/SIMD min) -> VGPR cap 64 -> 2 blocks/CU = 32 waves/CU (100%).
// Demand ~50 < 64, so the R5 spill mode shouldn't trigger (FETCH = tripwire).
__global__ __launch_bounds__(NTHR_, 8)
void lstm_mfma(const float* __restrict__ x,
               const float* __restrict__ W_ih,
               const float* __restrict__ W_hh,
               const float* __restrict__ b_ih,
               const float* __restrict__ b_hh,
               const float* __restrict__ W_fc,
               const float* __restrict__ b_fc,
               float* __restrict__ out)
{
    // weight A-fragments (K rows 0..63), fragment-linear (lane 16B-contiguous)
    __shared__ __align__(16) _Float16 wfrag[NTILE_ * NQ_ * 64 * 8];  // 26.6 KB
    // state ping-pong: st[buf][batch*KP_ + k]; k 0..15 = x, 16..65 = h, 66..71 = 0
    __shared__ __align__(16) _Float16 st[2][BPB_ * KP_];             // 4.6 KB

    const int tid  = threadIdx.x;
    const int lane = tid & 63;
    const int wv   = tid >> 6;          // 0..15
    const int b0   = blockIdx.x * BPB_;

    // ---- stage weight fragments (one time). slot s = 4u+kk (unit u, kind kk),
    //      A row (M) = lane&15, k = (lane>>4)*8 + e.
    u32* wf32 = (u32*)wfrag;
    for (int idx = tid; idx < NTILE_ * NQ_ * 256; idx += NTHR_) {
        const int j    = idx & 3;
        const int ln   = (idx >> 2) & 63;
        const int chnk = idx >> 8;                 // tile*2 + q
        const int tile = chnk >> 1, q = chnk & 1;
        const int s  = tile * 16 + (ln & 15);
        const int u_ = s >> 2, kk = s & 3;
        const int k0 = q * 32 + (ln >> 4) * 8 + 2 * j;
        float w0 = 0.f, w1 = 0.f;
        if (u_ < HID_) {
            const int g = kk * HID_ + u_;
            w0 = (k0 < IN_) ? W_ih[g * IN_ + k0] : W_hh[g * HID_ + (k0 - IN_)];
            w1 = (k0 + 1 < IN_) ? W_ih[g * IN_ + k0 + 1] : W_hh[g * HID_ + (k0 + 1 - IN_)];
        }
        wf32[idx] = pkh2(w0, w1);
    }
    // ---- zero both state buffers (h(0)=0; pad rows stay 0 forever)
    for (int idx = tid; idx < 2 * BPB_ * KPW_; idx += NTHR_)
        ((u32*)st)[idx] = 0u;

    // ---- compute-wave setup: wave wv<13 owns tile wv; lane -> unit u, batch lane&15
    const bool comp = (wv < NTILE_);
    const int  u    = 4 * wv + (lane >> 4);        // [0,51]; 50,51 = pad
    f32x4 bias = {0.f, 0.f, 0.f, 0.f};
    u32 wt0 = 0, wt1 = 0, wt2 = 0, wt3 = 0;        // tail weights (K rows 64,65)
    if (comp && u < HID_) {
        bias[0] = b_ih[u            ] + b_hh[u            ];
        bias[1] = b_ih[HID_     + u ] + b_hh[HID_     + u ];
        bias[2] = b_ih[2*HID_   + u ] + b_hh[2*HID_   + u ];
        bias[3] = b_ih[3*HID_   + u ] + b_hh[3*HID_   + u ];
        wt0 = pkh2(W_hh[(u          ) * HID_ + 48], W_hh[(u          ) * HID_ + 49]);
        wt1 = pkh2(W_hh[(HID_   + u ) * HID_ + 48], W_hh[(HID_   + u ) * HID_ + 49]);
        wt2 = pkh2(W_hh[(2*HID_ + u ) * HID_ + 48], W_hh[(2*HID_ + u ) * HID_ + 49]);
        wt3 = pkh2(W_hh[(3*HID_ + u ) * HID_ + 48], W_hh[(3*HID_ + u ) * HID_ + 49]);
    }
    float c_ = 0.f;

    const int bcol = lane & 15;
    const int brow = bcol * KP_ + (lane >> 4) * 8;        // B-fragment half index
    const int trow = bcol * KPW_ + 32;                    // u32 idx of K rows 64,65
    const int hrow = bcol * KP_ + IN_ + u;                // h writeback
    const _Float16* wbase = wfrag + (size_t)(wv * NQ_) * 512 + lane * 8;

    // ---- loader-wave setup: waves 13,14 stream x (128 lanes = 16b x 8 f-pairs)
    const int  L  = tid - NTILE_ * 64;
    const bool xl = (!comp) && (L < BPB_ * 8);
    const int  bq = (L >> 3) & 15, fq = L & 7;
    const float* xq = x + (size_t)(b0 + bq) * (T_ * IN_) + 2 * fq;
    const int  xo = bq * KPW_ + fq;                       // u32 index in st

    __syncthreads();                  // staging + zero visible
    if (xl) {
        const float2 v = *(const float2*)xq;
        ((u32*)st[0])[xo] = pkh2(v.x, v.y);
    }
    __syncthreads();                  // x(0) ready

    for (int t = 0; t < T_; ++t) {
        const _Float16* sc = st[t & 1];
        _Float16*       sn = st[(t & 1) ^ 1];

        if (comp) {
            const half8 B0 = *(const half8*)(sc + brow);
            const half8 B1 = *(const half8*)(sc + brow + 32);
            const u32   hT = ((const u32*)sc)[trow];
            const half8 A0 = *(const half8*)(wbase);
            const half8 A1 = *(const half8*)(wbase + 512);
            f32x4 C = bias;
            C = MFMA(A0, B0, C);
            C = MFMA(A1, B1, C);
            C[0] = FDOT2(hT, wt0, C[0]);
            C[1] = FDOT2(hT, wt1, C[1]);
            C[2] = FDOT2(hT, wt2, C[2]);
            C[3] = FDOT2(hT, wt3, C[3]);

            const float iv = sig1(C[0]), fv = sig1(C[1]);
            const float gv = tanh1(C[2]), ov = sig1(C[3]);
            c_ = fmaf(fv, c_, iv * gv);
            const float hv = ov * tanh1(c_);
            if (u < HID_) sn[hrow] = (_Float16)hv;
        } else if (xl && t + 1 < T_) {
            const float2 v = *(const float2*)(xq + (size_t)(t + 1) * IN_);
            ((u32*)sn)[xo] = pkh2(v.x, v.y);
        }
        __syncthreads();              // ONE barrier per step
    }

    // final h in st[0] (t=127 wrote buffer 0), fp16 rows 16..65
    const _Float16* hf = st[0];

    // ---- FC head: 16 batches x 20 classes (320 threads, single pass)
    if (tid < BPB_ * NCLS_) {
        const int b  = tid / NCLS_;
        const int cl = tid - b * NCLS_;
        float acc = b_fc[cl];
        #pragma unroll
        for (int j = 0; j < HID_; ++j) {
            const float hv = fmaxf((float)hf[b * KP_ + IN_ + j], 0.0f);   // relu
            acc = fmaf(hv, W_fc[cl * HID_ + j], acc);
        }
        out[(size_t)(b0 + b) * NCLS_ + cl] = acc;
    }
}

extern "C" void kernel_launch(void* const* d_in, const int* in_sizes, int n_in,
                              void* d_out, int out_size, void* d_ws, size_t ws_size,
                              hipStream_t stream) {
    const float* x    = (const float*)d_in[0];
    const float* W_ih = (const float*)d_in[1];
    const float* W_hh = (const float*)d_in[2];
    const float* b_ih = (const float*)d_in[3];
    const float* b_hh = (const float*)d_in[4];
    const float* W_fc = (const float*)d_in[5];
    const float* b_fc = (const float*)d_in[6];
    float* out = (float*)d_out;

    const int B = in_sizes[0] / (T_ * IN_);   // 8192
    dim3 grid(B / BPB_), block(NTHR_);
    hipLaunchKernelGGL(lstm_mfma, grid, block, 0, stream,
                       x, W_ih, W_hh, b_ih, b_hh, W_fc, b_fc, out);
}

// Round 11
// 103.178 us; speedup vs baseline: 312.5497x; 1.1189x over previous
//
#include <hip/hip_runtime.h>

#define IN_    16
#define HID_   50
#define T_     128
#define NCLS_  20
#define BPB_   16     // batches per block = MFMA N
#define NTHR_  1024   // 16 waves: 13 compute (1 M-tile each) + x-loader lanes
#define NTILE_ 13     // 13 tiles x 16 slots = 208 gate-slots (200 real)
#define NQ_    2      // K chunks of 32 -> K=64 via MFMA; rows 64,65 via fdot2 tail
#define KP_    72     // state row stride in halves (144B, 16B-aligned)
#define KPW_   36     // state row stride in u32

typedef _Float16 half8 __attribute__((ext_vector_type(8)));
typedef _Float16 h2_t  __attribute__((ext_vector_type(2)));
typedef float    f32x4 __attribute__((ext_vector_type(4)));
typedef unsigned int u32;

#define L2E_ 1.4426950408889634f
__device__ __forceinline__ h2_t as_h2(u32 v) { union { u32 u; h2_t h; } x; x.u = v; return x.h; }
__device__ __forceinline__ u32 pkh2(float a, float b) {
    union { u32 v; _Float16 h[2]; } p; p.h[0] = (_Float16)a; p.h[1] = (_Float16)b; return p.v;
}
#define FDOT2(S, W, ACC) __builtin_amdgcn_fdot2(as_h2(S), as_h2(W), (ACC), false)
#define MFMA(A, B, C) __builtin_amdgcn_mfma_f32_16x16x32_f16((A), (B), (C), 0, 0, 0)
// activation-domain helpers: inputs are PRE-SCALED by -log2e (sig) / -2log2e (tanh)
#define SIGS(v)  __builtin_amdgcn_rcpf(1.0f + __builtin_amdgcn_exp2f(v))
#define TANHS(v) fmaf(2.0f, __builtin_amdgcn_rcpf(1.0f + __builtin_amdgcn_exp2f(v)), -1.0f)

// (1024, 8 waves/SIMD) -> VGPR cap 64 -> 2 blocks/CU = 32 waves/CU.
// Demand ~48 < 64 (R5 spill rule: FETCH_SIZE is the tripwire).
__global__ __launch_bounds__(NTHR_, 8)
void lstm_mfma(const float* __restrict__ x,
               const float* __restrict__ W_ih,
               const float* __restrict__ W_hh,
               const float* __restrict__ b_ih,
               const float* __restrict__ b_hh,
               const float* __restrict__ W_fc,
               const float* __restrict__ b_fc,
               float* __restrict__ out)
{
    // weight A-fragments (K rows 0..63), fragment-linear; dead after reg preload
    __shared__ __align__(16) _Float16 wfrag[NTILE_ * NQ_ * 64 * 8];  // 26.6 KB
    // state ping-pong: st[buf][batch*KP_ + k]; k 0..15 = x, 16..65 = h, 66..71 = 0
    __shared__ __align__(16) _Float16 st[2][BPB_ * KP_];             // 4.6 KB

    const int tid  = threadIdx.x;
    const int lane = tid & 63;
    const int wv   = tid >> 6;          // 0..15
    const int b0   = blockIdx.x * BPB_;

    // ---- stage weight fragments, PRE-SCALED into activation domain.
    //      slot s = 4u+kk; A row (M) = lane&15, k = (lane>>4)*8 + e.
    u32* wf32 = (u32*)wfrag;
    for (int idx = tid; idx < NTILE_ * NQ_ * 256; idx += NTHR_) {
        const int j    = idx & 3;
        const int ln   = (idx >> 2) & 63;
        const int chnk = idx >> 8;                 // tile*2 + q
        const int tile = chnk >> 1, q = chnk & 1;
        const int s  = tile * 16 + (ln & 15);
        const int u_ = s >> 2, kk = s & 3;
        const int k0 = q * 32 + (ln >> 4) * 8 + 2 * j;
        float w0 = 0.f, w1 = 0.f;
        if (u_ < HID_) {
            const int g = kk * HID_ + u_;
            w0 = (k0 < IN_) ? W_ih[g * IN_ + k0] : W_hh[g * HID_ + (k0 - IN_)];
            w1 = (k0 + 1 < IN_) ? W_ih[g * IN_ + k0 + 1] : W_hh[g * HID_ + (k0 + 1 - IN_)];
        }
        const float sc_ = (kk == 2) ? (-2.0f * L2E_) : (-L2E_);
        wf32[idx] = pkh2(w0 * sc_, w1 * sc_);
    }
    // ---- zero both state buffers (h(0)=0; pad rows stay 0 forever)
    for (int idx = tid; idx < 2 * BPB_ * KPW_; idx += NTHR_)
        ((u32*)st)[idx] = 0u;

    // ---- compute-wave setup: wave wv<13 owns tile wv; lane -> unit u, batch lane&15
    const bool comp = (wv < NTILE_);
    const int  u    = 4 * wv + (lane >> 4);        // [0,51]; 50,51 = pad
    f32x4 bias = {0.f, 0.f, 0.f, 0.f};
    u32 wt0 = 0, wt1 = 0, wt2 = 0, wt3 = 0;        // tail weights (K rows 64,65), scaled
    if (comp && u < HID_) {
        bias[0] = (b_ih[u          ] + b_hh[u          ]) * -L2E_;
        bias[1] = (b_ih[HID_   + u ] + b_hh[HID_   + u ]) * -L2E_;
        bias[2] = (b_ih[2*HID_ + u ] + b_hh[2*HID_ + u ]) * (-2.0f * L2E_);
        bias[3] = (b_ih[3*HID_ + u ] + b_hh[3*HID_ + u ]) * -L2E_;
        wt0 = pkh2(W_hh[(u          ) * HID_ + 48] * -L2E_,          W_hh[(u          ) * HID_ + 49] * -L2E_);
        wt1 = pkh2(W_hh[(HID_   + u ) * HID_ + 48] * -L2E_,          W_hh[(HID_   + u ) * HID_ + 49] * -L2E_);
        wt2 = pkh2(W_hh[(2*HID_ + u ) * HID_ + 48] * (-2.0f * L2E_), W_hh[(2*HID_ + u ) * HID_ + 49] * (-2.0f * L2E_));
        wt3 = pkh2(W_hh[(3*HID_ + u ) * HID_ + 48] * -L2E_,          W_hh[(3*HID_ + u ) * HID_ + 49] * -L2E_);
    }
    float c_ = 0.f;

    const int bcol = lane & 15;
    const int brow = bcol * KP_ + (lane >> 4) * 8;        // B-fragment half index
    const int trow = bcol * KPW_ + 32;                    // u32 idx of K rows 64,65
    const int hrow = bcol * KP_ + IN_ + u;                // h writeback
    const _Float16* wbase = wfrag + (size_t)(wv * NQ_) * 512 + lane * 8;

    // ---- loader lanes: 128 threads of waves 13/14 stream x (16 b x 8 f-pairs)
    const int  L  = tid - NTILE_ * 64;
    const bool xl = (!comp) && (L >= 0) && (L < BPB_ * 8);
    const int  bq = (L >> 3) & 15, fq = L & 7;
    const float* xq = x + (size_t)(b0 + bq) * (T_ * IN_) + 2 * fq;
    const int  xo = bq * KPW_ + fq;                       // u32 index in st

    __syncthreads();                  // staging + zero visible

    // ---- A-fragments -> VGPRs once (weights are loop-invariant; kills the
    //      2 ds_read_b128/wave/step that dominated R10's LDS traffic)
    half8 A0 = {}, A1 = {};
    if (comp) {
        A0 = *(const half8*)(wbase);
        A1 = *(const half8*)(wbase + 512);
    }
    if (xl) {
        const float2 v = *(const float2*)xq;
        ((u32*)st[0])[xo] = pkh2(v.x, v.y);
    }
    __syncthreads();                  // x(0) ready

    for (int t = 0; t < T_; ++t) {
        const _Float16* sc = st[t & 1];
        _Float16*       sn = st[(t & 1) ^ 1];

        if (comp) {
            const half8 B0 = *(const half8*)(sc + brow);
            const half8 B1 = *(const half8*)(sc + brow + 32);
            const u32   hT = ((const u32*)sc)[trow];
            f32x4 C = MFMA(A0, B0, bias);
            C = MFMA(A1, B1, C);
            C[0] = FDOT2(hT, wt0, C[0]);
            C[1] = FDOT2(hT, wt1, C[1]);
            C[2] = FDOT2(hT, wt2, C[2]);
            C[3] = FDOT2(hT, wt3, C[3]);

            // C is already in activation domain (pre-scaled weights)
            const float iv = SIGS(C[0]);
            const float fv = SIGS(C[1]);
            const float gv = TANHS(C[2]);
            const float ov = SIGS(C[3]);
            c_ = fmaf(fv, c_, iv * gv);
            const float hv = ov * TANHS(c_ * (-2.0f * L2E_));
            if (u < HID_) sn[hrow] = (_Float16)hv;
        } else if (xl && t + 1 < T_) {
            const float2 v = *(const float2*)(xq + (size_t)(t + 1) * IN_);
            ((u32*)sn)[xo] = pkh2(v.x, v.y);
        }
        __syncthreads();              // ONE barrier per step
    }

    // final h in st[0] (t=127 wrote buffer 0), fp16 rows 16..65
    const _Float16* hf = st[0];

    // ---- FC head: 16 batches x 20 classes (320 threads, single pass)
    if (tid < BPB_ * NCLS_) {
        const int b  = tid / NCLS_;
        const int cl = tid - b * NCLS_;
        float acc = b_fc[cl];
        #pragma unroll
        for (int j = 0; j < HID_; ++j) {
            const float hv = fmaxf((float)hf[b * KP_ + IN_ + j], 0.0f);   // relu
            acc = fmaf(hv, W_fc[cl * HID_ + j], acc);
        }
        out[(size_t)(b0 + b) * NCLS_ + cl] = acc;
    }
}

extern "C" void kernel_launch(void* const* d_in, const int* in_sizes, int n_in,
                              void* d_out, int out_size, void* d_ws, size_t ws_size,
                              hipStream_t stream) {
    const float* x    = (const float*)d_in[0];
    const float* W_ih = (const float*)d_in[1];
    const float* W_hh = (const float*)d_in[2];
    const float* b_ih = (const float*)d_in[3];
    const float* b_hh = (const float*)d_in[4];
    const float* W_fc = (const float*)d_in[5];
    const float* b_fc = (const float*)d_in[6];
    float* out = (float*)d_out;

    const int B = in_sizes[0] / (T_ * IN_);   // 8192
    dim3 grid(B / BPB_), block(NTHR_);
    hipLaunchKernelGGL(lstm_mfma, grid, block, 0, stream,
                       x, W_ih, W_hh, b_ih, b_hh, W_fc, b_fc, out);
}